// Round 6
// baseline (452.690 us; speedup 1.0000x reference)
//
#include <hip/hip_runtime.h>
#include <hip/hip_bf16.h>
#include <stdint.h>

#define M_DIM 8192
#define N_DIM 4096
#define K_DIM 4096
#define FP8MAX 448.0f
#define CANARY 0x5CA1AB1Eu

typedef float floatx4 __attribute__((ext_vector_type(4)));
typedef float floatx16 __attribute__((ext_vector_type(16)));
typedef short short8 __attribute__((ext_vector_type(8)));
typedef int int8v __attribute__((ext_vector_type(8)));

// f32 -> bf16 bits, RNE. Exact for fp8-grid values. (fallback path)
__device__ __forceinline__ unsigned int f2bfbits(float f) {
    union { float f; unsigned int u; } v; v.f = f;
    return (v.u + 0x7fffu + ((v.u >> 16) & 1u)) >> 16;
}

// fp32x4 -> e4m3(RNE,sat) -> bf16x4 packed into uint2 (fallback path)
__device__ __forceinline__ uint2 quant4(float a, float b, float c, float d) {
    int p8 = __builtin_amdgcn_cvt_pk_fp8_f32(a, b, 0, false);
    p8 = __builtin_amdgcn_cvt_pk_fp8_f32(c, d, p8, true);
    float qa = __builtin_amdgcn_cvt_f32_fp8(p8, 0);
    float qb = __builtin_amdgcn_cvt_f32_fp8(p8, 1);
    float qc = __builtin_amdgcn_cvt_f32_fp8(p8, 2);
    float qd = __builtin_amdgcn_cvt_f32_fp8(p8, 3);
    return make_uint2(f2bfbits(qa) | (f2bfbits(qb) << 16),
                      f2bfbits(qc) | (f2bfbits(qd) << 16));
}

// uint4 of 4 fp32 -> 4 packed e4m3 bytes (RNE, saturating)
__device__ __forceinline__ unsigned int q4(uint4 v) {
    int p8 = __builtin_amdgcn_cvt_pk_fp8_f32(__uint_as_float(v.x), __uint_as_float(v.y), 0, false);
    p8 = __builtin_amdgcn_cvt_pk_fp8_f32(__uint_as_float(v.z), __uint_as_float(v.w), p8, true);
    return (unsigned int)p8;
}

__device__ __forceinline__ float amax4(uint4 v, float m) {
    float a = fabsf(__uint_as_float(v.x)), b = fabsf(__uint_as_float(v.y));
    float c = fabsf(__uint_as_float(v.z)), d = fabsf(__uint_as_float(v.w));
    return fmaxf(m, fmaxf(fmaxf(a, b), fmaxf(c, d)));
}

// ============ Fused prepass: w-quant (blocks 0..1023) + x-quant+absmax ============
__global__ __launch_bounds__(256) void quant_fused(const uint4* __restrict__ x,
                                                   const uint4* __restrict__ w,
                                                   uint4* __restrict__ xq,
                                                   uint4* __restrict__ wq,
                                                   unsigned int* __restrict__ scb) {
    if (blockIdx.x < 1024) {
        const int tid = blockIdx.x * 256 + threadIdx.x;
        for (int c = tid; c < (N_DIM * K_DIM) / 16; c += 1024 * 256) {
            uint4 v0 = w[4 * c + 0], v1 = w[4 * c + 1];
            uint4 v2 = w[4 * c + 2], v3 = w[4 * c + 3];
            wq[c] = make_uint4(q4(v0), q4(v1), q4(v2), q4(v3));
        }
    } else {
        const int b = blockIdx.x - 1024;
        const int tid = b * 256 + threadIdx.x;
        float vmax = 0.f;
        for (int c = tid; c < (M_DIM * K_DIM) / 16; c += 2048 * 256) {
            uint4 v0 = x[4 * c + 0], v1 = x[4 * c + 1];
            uint4 v2 = x[4 * c + 2], v3 = x[4 * c + 3];
            vmax = amax4(v0, vmax); vmax = amax4(v1, vmax);
            vmax = amax4(v2, vmax); vmax = amax4(v3, vmax);
            xq[c] = make_uint4(q4(v0), q4(v1), q4(v2), q4(v3));
        }
        #pragma unroll
        for (int off = 32; off >= 1; off >>= 1)
            vmax = fmaxf(vmax, __shfl_xor(vmax, off, 64));
        __shared__ float smax[4];
        if ((threadIdx.x & 63) == 0) smax[threadIdx.x >> 6] = vmax;
        __syncthreads();
        if (threadIdx.x == 0) {
            float m = fmaxf(fmaxf(smax[0], smax[1]), fmaxf(smax[2], smax[3]));
            atomicMax(scb, __float_as_uint(m));   // bits monotonic for m >= 0
        }
    }
}

__device__ __forceinline__ int8v pack8(uint4 u0, uint4 u1) {
    int8v r;
    r[0] = (int)u0.x; r[1] = (int)u0.y; r[2] = (int)u0.z; r[3] = (int)u0.w;
    r[4] = (int)u1.x; r[5] = (int)u1.y; r[6] = (int)u1.z; r[7] = (int)u1.w;
    return r;
}

// ========== FP8 GEMM: 256x256 tile, BK=128B, 8 waves (2Mx4N), 8-phase schedule
// (m201 template port). Per-wave out 128x64 = acc[4][2] of 32x32. LDS 128KB =
// 2 dbuf x (A 32KB + B 32KB); proven (row&7)<<4 XOR swizzle (stage-source +
// read). Per phase: {ds_read subtile || stage 1 half-tile (2 gload_lds) ->
// barrier -> setprio(1) -> 4 MFMA -> setprio(0) -> barrier}. Quadrant order
// m0n0,m0n1,m1n0,m1n1 => B dead after ph2, A dead after ph3. Stage rotation
// (target provably dead >=1 closed phase before issue):
//  ph1:A1'->buf1(t1) ph2:B1'->buf1(t1) ph3:B0->buf0(t2) ph4:A0->buf0(t2)
//  ph5:A1->buf0(t2)  ph6:B1->buf0(t2)  ph7:B0'->buf1(t3) ph8:A0'->buf1(t3)
// Ledger (2 loads/thread/phase): vmcnt(4) at ph4 and ph8 waits exactly the
// needed tile's 8 loads, leaves 2 half-tiles in flight. vmcnt(0) at it==15 ph4.
__global__ __launch_bounds__(512, 2) void gemm_fp8_kernel(
    const unsigned char* __restrict__ Aq,   // [8192][4096] e4m3 bytes
    const unsigned char* __restrict__ Bq,   // [4096][4096] e4m3 bytes
    const unsigned int* __restrict__ scb,   // absmax(x) bits
    const float* __restrict__ wscale,
    const float* __restrict__ bias,
    float* __restrict__ out) {
    __shared__ __align__(16) unsigned char lds[131072];  // buf b: A @b*65536, B @b*65536+32768
    const int tid = threadIdx.x;
    const int l = tid & 63, wv = tid >> 3 >> 3;          // 8 waves
    const int wm = wv >> 2, wn = wv & 3;                 // 2M x 4N wave grid
    const int la = l & 31, klo = (l >> 5) * 32;

    // XCD-aware bijective remap: 512 wgs, XCD k owns bm in [4k,4k+4)
    const int lin = blockIdx.y * 16 + blockIdx.x;        // 0..511
    const int wg = (lin & 7) * 64 + (lin >> 3);
    const int bm = wg >> 4, bn = wg & 15;

    const float am = __uint_as_float(*scb);
    const float scl = (fmaxf(am, 1e-12f) / FP8MAX) * wscale[0];

    // ---- staging map (proven r3): wave w instr i half h -> rows h*128+16w+8i+(l>>3),
    //      source col 16(l&7) ^ ((l>>3)<<4) (row&7 == l>>3); LDS dest linear ----
    const int srow = l >> 3;
    const int scol = (16 * (l & 7)) ^ (srow << 4);
    const unsigned char* gAb = Aq + (size_t)(bm * 256 + 16 * wv + srow) * 4096 + scol;
    const unsigned char* gBb = Bq + (size_t)(bn * 256 + 16 * wv + srow) * 4096 + scol;
    const int swzR = (l & 7) << 4;

#define AS1 __attribute__((address_space(1)))
#define AS3 __attribute__((address_space(3)))
#define STA(h, t, b) do { \
    const unsigned char* g_ = gAb + (size_t)(h) * 524288 + (t) * 128; \
    unsigned char* d_ = lds + (b) * 65536 + (h) * 16384 + wv * 2048; \
    __builtin_amdgcn_global_load_lds((const AS1 void*)g_, (AS3 void*)d_, 16, 0, 0); \
    __builtin_amdgcn_global_load_lds((const AS1 void*)(g_ + 32768), (AS3 void*)(d_ + 1024), 16, 0, 0); \
} while (0)
#define STB(h, t, b) do { \
    const unsigned char* g_ = gBb + (size_t)(h) * 524288 + (t) * 128; \
    unsigned char* d_ = lds + (b) * 65536 + 32768 + (h) * 16384 + wv * 2048; \
    __builtin_amdgcn_global_load_lds((const AS1 void*)g_, (AS3 void*)d_, 16, 0, 0); \
    __builtin_amdgcn_global_load_lds((const AS1 void*)(g_ + 32768), (AS3 void*)(d_ + 1024), 16, 0, 0); \
} while (0)
#define RD16(dst, base, off) dst = pack8(*(const uint4*)((base) + ((off) ^ swzR)), \
                                         *(const uint4*)((base) + (((off) + 16) ^ swzR)))
#define READA(b, mh) do { \
    const unsigned char* pa0_ = lds + (b) * 65536 + (wm * 128 + (mh) * 64 + la) * 128; \
    const unsigned char* pa1_ = pa0_ + 32 * 128; \
    RD16(af[0][0], pa0_, klo); RD16(af[0][1], pa0_, 64 + klo); \
    RD16(af[1][0], pa1_, klo); RD16(af[1][1], pa1_, 64 + klo); \
} while (0)
#define READB(b, nj) do { \
    const unsigned char* pb_ = lds + (b) * 65536 + 32768 + (wn * 64 + (nj) * 32 + la) * 128; \
    RD16(bf[nj][0], pb_, klo); RD16(bf[nj][1], pb_, 64 + klo); \
} while (0)
#define MFMA1(ai, nj, s) acc[ai][nj] = __builtin_amdgcn_mfma_scale_f32_32x32x64_f8f6f4( \
    af[(ai) & 1][s], bf[nj][s], acc[ai][nj], 0, 0, 0, 0x7F, 0, 0x7F)
#define MFMA4(mh, nj) do { \
    MFMA1(2 * (mh), nj, 0); MFMA1(2 * (mh) + 1, nj, 0); \
    MFMA1(2 * (mh), nj, 1); MFMA1(2 * (mh) + 1, nj, 1); \
} while (0)
#define BARRIER() asm volatile("s_barrier" ::: "memory")
#define VMCNT4() asm volatile("s_waitcnt vmcnt(4)" ::: "memory")
#define VMCNT0() asm volatile("s_waitcnt vmcnt(0)" ::: "memory")
#define MIDBAR() do { BARRIER(); __builtin_amdgcn_sched_barrier(0); \
                      __builtin_amdgcn_s_setprio(1); } while (0)
#define ENDPH()  do { __builtin_amdgcn_s_setprio(0); BARRIER(); } while (0)

    floatx16 acc[4][2];
    #pragma unroll
    for (int i = 0; i < 4; ++i) { acc[i][0] = (floatx16)0.f; acc[i][1] = (floatx16)0.f; }
    int8v af[2][2], bf[2][2];

    // ---- prologue: tile0 (4 halves -> buf0), tile1 B0',A0' -> buf1; 12 loads ----
    STB(0, 0, 0); STA(0, 0, 0); STA(1, 0, 0); STB(1, 0, 0);
    STB(0, 1, 1); STA(0, 1, 1);
    VMCNT4();                  // tile0's 8 landed; tile1's 4 in flight
    BARRIER();

    for (int it = 0; it < 16; ++it) {
        const int t1 = 2 * it + 1, t2 = 2 * it + 2, t3 = 2 * it + 3;
        const bool st = (it < 15);
        // ---- ph1: Q(m0,n0) from buf0 ----
        READA(0, 0); READB(0, 0);
        STA(1, t1, 1);
        MIDBAR(); MFMA4(0, 0); ENDPH();
        // ---- ph2: Q(m0,n1) ----
        READB(0, 1);
        STB(1, t1, 1);
        MIDBAR(); MFMA4(0, 1); ENDPH();
        // ---- ph3: Q(m1,n0) ----
        READA(0, 1);
        if (st) STB(0, t2, 0);
        MIDBAR(); MFMA4(1, 0); ENDPH();
        // ---- ph4: Q(m1,n1); tile-boundary wait ----
        if (st) STA(0, t2, 0);
        BARRIER(); __builtin_amdgcn_sched_barrier(0);
        __builtin_amdgcn_s_setprio(1); MFMA4(1, 1); __builtin_amdgcn_s_setprio(0);
        if (it == 15) { VMCNT0(); } else { VMCNT4(); }   // buf1 = tile t1 ready
        BARRIER();
        // ---- ph5: Q(m0,n0) from buf1 ----
        READA(1, 0); READB(1, 0);
        if (st) STA(1, t2, 0);
        MIDBAR(); MFMA4(0, 0); ENDPH();
        // ---- ph6: Q(m0,n1) ----
        READB(1, 1);
        if (st) STB(1, t2, 0);
        MIDBAR(); MFMA4(0, 1); ENDPH();
        // ---- ph7: Q(m1,n0) ----
        READA(1, 1);
        if (st) STB(0, t3, 1);
        MIDBAR(); MFMA4(1, 0); ENDPH();
        // ---- ph8: Q(m1,n1); tile-boundary wait ----
        if (st) STA(0, t3, 1);
        BARRIER(); __builtin_amdgcn_sched_barrier(0);
        __builtin_amdgcn_s_setprio(1); MFMA4(1, 1); __builtin_amdgcn_s_setprio(0);
        if (st) { VMCNT4(); }                            // buf0 = tile t2 ready
        BARRIER();
    }

    // discriminator. Expected scl ~ 3.1e-6.
    float marker = 0.f;
    if (scl != scl || fabsf(scl) > 1e-1f) marker = 1000.f;
    else if (fabsf(scl) > 1e-4f) marker = 777.f;
    else if (fabsf(scl) < 1e-8f) marker = 333.f;

    float bj[2];
    #pragma unroll
    for (int j = 0; j < 2; ++j)
        bj[j] = bias[bn * 256 + wn * 64 + j * 32 + la];

    // C/D map (32x32): col=lane&31, row=(reg&3)+8*(reg>>2)+4*(lane>>5)
    #pragma unroll
    for (int ai = 0; ai < 4; ++ai) {
        #pragma unroll
        for (int rg = 0; rg < 4; ++rg) {
            #pragma unroll
            for (int rr = 0; rr < 4; ++rr) {
                int row = bm * 256 + wm * 128 + ai * 32 + rg * 8 + rr + 4 * (l >> 5);
                float* orow = out + (size_t)row * N_DIM;
                #pragma unroll
                for (int j = 0; j < 2; ++j) {
                    int col = bn * 256 + wn * 64 + j * 32 + la;
                    float v = acc[ai][j][rg * 4 + rr] * scl + bj[j];
                    if (marker != 0.f) v = marker;
                    else if (bj[j] != bj[j]) v = 111.f;
                    else if (v != v) v = 555.f;
                    orow[col] = v;
                }
            }
        }
    }
}

// ================= Fallback (in-place spread) path: round-6 verbatim =================

__global__ __launch_bounds__(256) void quant_w_kernel(unsigned char* wbuf) {
    const size_t t = (size_t)blockIdx.x * 256 + threadIdx.x;
    uint4* p = (uint4*)(wbuf + t * 256);
    uint4 r[16];
    #pragma unroll
    for (int i = 0; i < 16; ++i) r[i] = p[i];
    const float* f = (const float*)r;
    unsigned int o[32];
    #pragma unroll
    for (int i = 0; i < 16; ++i) {
        unsigned int b0 = f2bfbits(f[4 * i + 0]);
        unsigned int b1 = f2bfbits(f[4 * i + 1]);
        unsigned int b2 = f2bfbits(f[4 * i + 2]);
        unsigned int b3 = f2bfbits(f[4 * i + 3]);
        ((uint2*)o)[i] = make_uint2(b0 | (b1 << 16), b2 | (b3 << 16));
    }
    uint4* q = (uint4*)(wbuf + t * 256);
    #pragma unroll
    for (int i = 0; i < 8; ++i) q[i] = ((uint4*)o)[i];
}

__global__ __launch_bounds__(256) void quant_x_kernel(unsigned char* xbuf, unsigned char* wbuf) {
    const size_t t = (size_t)blockIdx.x * 256 + threadIdx.x;
    uint4* p = (uint4*)(xbuf + t * 256);
    uint4 r[16];
    #pragma unroll
    for (int i = 0; i < 16; ++i) r[i] = p[i];
    const float* f = (const float*)r;
    float vmax = 0.f;
    unsigned int o[32];
    #pragma unroll
    for (int i = 0; i < 16; ++i) {
        float a = f[4 * i + 0], b = f[4 * i + 1], c = f[4 * i + 2], d = f[4 * i + 3];
        vmax = fmaxf(vmax, fmaxf(fmaxf(fabsf(a), fabsf(b)), fmaxf(fabsf(c), fabsf(d))));
        ((uint2*)o)[i] = quant4(a, b, c, d);
    }
    uint4* q = (uint4*)(xbuf + t * 256);
    #pragma unroll
    for (int i = 0; i < 8; ++i) q[i] = ((uint4*)o)[i];
    #pragma unroll
    for (int off = 32; off >= 1; off >>= 1)
        vmax = fmaxf(vmax, __shfl_xor(vmax, off, 64));
    __shared__ float smax[4];
    if ((threadIdx.x & 63) == 0) smax[threadIdx.x >> 6] = vmax;
    __syncthreads();
    if (threadIdx.x == 0)
        *(float*)(wbuf + ((size_t)blockIdx.x + 1) * 256 + 128) =
            fmaxf(fmaxf(smax[0], smax[1]), fmaxf(smax[2], smax[3]));
}

__global__ __launch_bounds__(256) void scale_kernel(unsigned char* wbuf, const float* wscale) {
    float vmax = 0.f;
    for (int i = threadIdx.x; i < 2048; i += 256)
        vmax = fmaxf(vmax, *(const float*)(wbuf + ((size_t)i + 1) * 256 + 128));
    #pragma unroll
    for (int off = 32; off >= 1; off >>= 1)
        vmax = fmaxf(vmax, __shfl_xor(vmax, off, 64));
    __shared__ float smax[4];
    if ((threadIdx.x & 63) == 0) smax[threadIdx.x >> 6] = vmax;
    __syncthreads();
    if (threadIdx.x == 0) {
        float m = fmaxf(fmaxf(smax[0], smax[1]), fmaxf(smax[2], smax[3]));
        *(float*)(wbuf + 128) = (fmaxf(m, 1e-12f) / FP8MAX) * wscale[0];
        *(unsigned int*)(wbuf + 132) = CANARY;
    }
}

// ========== Fallback GEMM: round-6 structure, strides parametrized ==========
__global__ __launch_bounds__(256, 2) void gemm_bf16_kernel(
    const unsigned char* __restrict__ Aq,
    const unsigned char* __restrict__ Bq,
    int rs, int ktb,
    const unsigned char* __restrict__ scb,
    const float* __restrict__ bias,
    float* __restrict__ out) {
    __shared__ __align__(16) short lds[2 * 128 * 72];
    const int tid = threadIdx.x;
    const int l = tid & 63, wv = tid >> 6, wm = wv >> 1, wn = wv & 1;
    const int bm = blockIdx.y, bn = blockIdx.x;
    const int r = tid >> 1, kq = (tid & 1) * 64;

    const float scl = *(const float*)scb;
    const unsigned int canary = *(const unsigned int*)(scb + 4);

    const unsigned char* gA = Aq + (size_t)(bm * 128 + r) * rs + kq;
    const unsigned char* gB = Bq + (size_t)(bn * 128 + r) * rs + kq;
    short* sA = lds + r * 72 + kq / 2;
    short* sB = lds + 9216 + r * 72 + kq / 2;

    int aOff[4][2], bOff[4][2];
    #pragma unroll
    for (int i = 0; i < 4; ++i) {
        #pragma unroll
        for (int s = 0; s < 2; ++s) {
            int rowa = wm * 64 + i * 16 + (l & 15);
            aOff[i][s] = rowa * 72 + s * 32 + (l >> 4) * 8;
            int rowb = wn * 64 + i * 16 + (l & 15);
            bOff[i][s] = 9216 + rowb * 72 + s * 32 + (l >> 4) * 8;
        }
    }

    floatx4 acc[4][4];
    #pragma unroll
    for (int i = 0; i < 4; ++i)
        #pragma unroll
        for (int j = 0; j < 4; ++j)
            acc[i][j] = (floatx4)0.f;

    for (int kt = 0; kt < K_DIM / 64; ++kt) {
        uint4 a0 = *(const uint4*)(gA);
        uint4 a1 = *(const uint4*)(gA + 16);
        uint4 a2 = *(const uint4*)(gA + 32);
        uint4 a3 = *(const uint4*)(gA + 48);
        uint4 b0 = *(const uint4*)(gB);
        uint4 b1 = *(const uint4*)(gB + 16);
        uint4 b2 = *(const uint4*)(gB + 32);
        uint4 b3 = *(const uint4*)(gB + 48);
        gA += ktb;
        gB += ktb;
        __syncthreads();
        *(uint4*)(sA +  0) = a0;  *(uint4*)(sA +  8) = a1;
        *(uint4*)(sA + 16) = a2;  *(uint4*)(sA + 24) = a3;
        *(uint4*)(sB +  0) = b0;  *(uint4*)(sB +  8) = b1;
        *(uint4*)(sB + 16) = b2;  *(uint4*)(sB + 24) = b3;
        __syncthreads();

        short8 af[4][2], bf[4][2];
        #pragma unroll
        for (int i = 0; i < 4; ++i) {
            af[i][0] = *(const short8*)(lds + aOff[i][0]);
            af[i][1] = *(const short8*)(lds + aOff[i][1]);
            bf[i][0] = *(const short8*)(lds + bOff[i][0]);
            bf[i][1] = *(const short8*)(lds + bOff[i][1]);
        }
        #pragma unroll
        for (int s = 0; s < 2; ++s)
            #pragma unroll
            for (int i = 0; i < 4; ++i)
                #pragma unroll
                for (int j = 0; j < 4; ++j)
                    acc[i][j] = __builtin_amdgcn_mfma_f32_16x16x32_bf16(
                        af[i][s], bf[j][s], acc[i][j], 0, 0, 0);
    }

    float marker = 0.f;
    if (canary != CANARY) marker = 222.f;
    else if (scl != scl || fabsf(scl) > 1e-1f) marker = 1000.f;
    else if (fabsf(scl) > 1e-4f) marker = 777.f;
    else if (fabsf(scl) < 1e-8f) marker = 333.f;

    float bj[4];
    #pragma unroll
    for (int j = 0; j < 4; ++j) {
        int col = bn * 128 + wn * 64 + j * 16 + (l & 15);
        bj[j] = bias[col];
    }
    #pragma unroll
    for (int i = 0; i < 4; ++i) {
        #pragma unroll
        for (int rr = 0; rr < 4; ++rr) {
            int row = bm * 128 + wm * 64 + i * 16 + (l >> 4) * 4 + rr;
            float* orow = out + (size_t)row * N_DIM;
            #pragma unroll
            for (int j = 0; j < 4; ++j) {
                int col = bn * 128 + wn * 64 + j * 16 + (l & 15);
                float v = acc[i][j][rr] * scl + bj[j];
                if (marker != 0.f) v = marker;
                else if (bj[j] != bj[j]) v = 111.f;
                else if (v != v) v = 555.f;
                orow[col] = v;
            }
        }
    }
}

extern "C" void kernel_launch(void* const* d_in, const int* in_sizes, int n_in,
                              void* d_out, int out_size, void* d_ws, size_t ws_size,
                              hipStream_t stream) {
    unsigned char* x = (unsigned char*)d_in[0];   // fp32 [8192][4096] (fp16 promoted)
    unsigned char* w = (unsigned char*)d_in[1];   // fp32 exact-fp8 [4096][4096]
    const float* wscale = (const float*)d_in[2];  // fp32 [1]
    const float* bias = (const float*)d_in[3];    // fp32 [4096] (fp16 promoted)
    float* out = (float*)d_out;                   // fp32 [8192][4096]

    const size_t XQ8 = (size_t)M_DIM * K_DIM;     // 32MB fp8 x
    const size_t WQ8 = (size_t)N_DIM * K_DIM;     // 16MB fp8 w
    unsigned char* ws = (unsigned char*)d_ws;

    if (ws_size >= XQ8 + WQ8 + 64) {
        // ---- fp8 compact path: memset(scale) + fused prepass + 8-phase MX-fp8 GEMM ----
        unsigned char* xq = ws;
        unsigned char* wq = ws + XQ8;
        unsigned int* scb = (unsigned int*)(ws + XQ8 + WQ8);
        hipMemsetAsync(scb, 0, 4, stream);        // seed for atomicMax (graph-safe)
        quant_fused<<<3072, 256, 0, stream>>>((const uint4*)x, (const uint4*)w,
                                              (uint4*)xq, (uint4*)wq, scb);
        gemm_fp8_kernel<<<dim3(N_DIM / 256, M_DIM / 256), 512, 0, stream>>>(
            xq, wq, scb, wscale, bias, out);
    } else {
        // ---- fallback: round-6 in-place spread path (proven) ----
        quant_w_kernel<<<1024, 256, 0, stream>>>(w);
        quant_x_kernel<<<2048, 256, 0, stream>>>(x, w);
        scale_kernel<<<1, 256, 0, stream>>>(w, wscale);
        gemm_bf16_kernel<<<dim3(N_DIM / 128, M_DIM / 128), 256, 0, stream>>>(
            x, w, 16384, 256, w + 128, bias, out);
    }
}

// Round 7
// 412.129 us; speedup vs baseline: 1.0984x; 1.0984x over previous
//
#include <hip/hip_runtime.h>
#include <hip/hip_bf16.h>
#include <stdint.h>

#define M_DIM 8192
#define N_DIM 4096
#define K_DIM 4096
#define FP8MAX 448.0f
#define CANARY 0x5CA1AB1Eu

typedef float floatx4 __attribute__((ext_vector_type(4)));
typedef float floatx16 __attribute__((ext_vector_type(16)));
typedef short short8 __attribute__((ext_vector_type(8)));
typedef int int8v __attribute__((ext_vector_type(8)));

// f32 -> bf16 bits, RNE. Exact for fp8-grid values. (fallback path)
__device__ __forceinline__ unsigned int f2bfbits(float f) {
    union { float f; unsigned int u; } v; v.f = f;
    return (v.u + 0x7fffu + ((v.u >> 16) & 1u)) >> 16;
}

// fp32x4 -> e4m3(RNE,sat) -> bf16x4 packed into uint2 (fallback path)
__device__ __forceinline__ uint2 quant4(float a, float b, float c, float d) {
    int p8 = __builtin_amdgcn_cvt_pk_fp8_f32(a, b, 0, false);
    p8 = __builtin_amdgcn_cvt_pk_fp8_f32(c, d, p8, true);
    float qa = __builtin_amdgcn_cvt_f32_fp8(p8, 0);
    float qb = __builtin_amdgcn_cvt_f32_fp8(p8, 1);
    float qc = __builtin_amdgcn_cvt_f32_fp8(p8, 2);
    float qd = __builtin_amdgcn_cvt_f32_fp8(p8, 3);
    return make_uint2(f2bfbits(qa) | (f2bfbits(qb) << 16),
                      f2bfbits(qc) | (f2bfbits(qd) << 16));
}

// uint4 of 4 fp32 -> 4 packed e4m3 bytes (RNE, saturating)
__device__ __forceinline__ unsigned int q4(uint4 v) {
    int p8 = __builtin_amdgcn_cvt_pk_fp8_f32(__uint_as_float(v.x), __uint_as_float(v.y), 0, false);
    p8 = __builtin_amdgcn_cvt_pk_fp8_f32(__uint_as_float(v.z), __uint_as_float(v.w), p8, true);
    return (unsigned int)p8;
}

__device__ __forceinline__ float amax4(uint4 v, float m) {
    float a = fabsf(__uint_as_float(v.x)), b = fabsf(__uint_as_float(v.y));
    float c = fabsf(__uint_as_float(v.z)), d = fabsf(__uint_as_float(v.w));
    return fmaxf(m, fmaxf(fmaxf(a, b), fmaxf(c, d)));
}

// ============ Fused prepass: w-quant (blocks 0..1023) + x-quant+absmax ============
// x absmax published via device-scope atomicMax on positive-float bits (monotonic
// for >=0 floats); scb[0] pre-zeroed by a 4-byte hipMemsetAsync in kernel_launch.
__global__ __launch_bounds__(256) void quant_fused(const uint4* __restrict__ x,
                                                   const uint4* __restrict__ w,
                                                   uint4* __restrict__ xq,
                                                   uint4* __restrict__ wq,
                                                   unsigned int* __restrict__ scb) {
    if (blockIdx.x < 1024) {
        const int tid = blockIdx.x * 256 + threadIdx.x;
        for (int c = tid; c < (N_DIM * K_DIM) / 16; c += 1024 * 256) {
            uint4 v0 = w[4 * c + 0], v1 = w[4 * c + 1];
            uint4 v2 = w[4 * c + 2], v3 = w[4 * c + 3];
            wq[c] = make_uint4(q4(v0), q4(v1), q4(v2), q4(v3));
        }
    } else {
        const int b = blockIdx.x - 1024;
        const int tid = b * 256 + threadIdx.x;
        float vmax = 0.f;
        for (int c = tid; c < (M_DIM * K_DIM) / 16; c += 2048 * 256) {
            uint4 v0 = x[4 * c + 0], v1 = x[4 * c + 1];
            uint4 v2 = x[4 * c + 2], v3 = x[4 * c + 3];
            vmax = amax4(v0, vmax); vmax = amax4(v1, vmax);
            vmax = amax4(v2, vmax); vmax = amax4(v3, vmax);
            xq[c] = make_uint4(q4(v0), q4(v1), q4(v2), q4(v3));
        }
        #pragma unroll
        for (int off = 32; off >= 1; off >>= 1)
            vmax = fmaxf(vmax, __shfl_xor(vmax, off, 64));
        __shared__ float smax[4];
        if ((threadIdx.x & 63) == 0) smax[threadIdx.x >> 6] = vmax;
        __syncthreads();
        if (threadIdx.x == 0) {
            float m = fmaxf(fmaxf(smax[0], smax[1]), fmaxf(smax[2], smax[3]));
            atomicMax(scb, __float_as_uint(m));   // bits monotonic for m >= 0
        }
    }
}

__device__ __forceinline__ int8v pack8(uint4 u0, uint4 u1) {
    int8v r;
    r[0] = (int)u0.x; r[1] = (int)u0.y; r[2] = (int)u0.z; r[3] = (int)u0.w;
    r[4] = (int)u1.x; r[5] = (int)u1.y; r[6] = (int)u1.z; r[7] = (int)u1.w;
    return r;
}

// ========== FP8 GEMM: round-3 geometry (128x128 tile, 4 waves, 64x64/wave,
// gload_lds + XOR swizzle, byte-identical read path) with the catalog's
// T3-minimum pipeline: 2-buffer LDS (2x32KB), ONE barrier per K-tile, and the
// vmcnt(0) wait placed AFTER compute:
//   stage(t+1); compute(t); vmcnt(0); barrier;
// => the 8 staging loads fly during ~700cy of ds_read+MFMA instead of being
// drained immediately after issue (r3: __syncthreads drain right after issue;
// r5: vmcnt(8) right after issue — both exposed full staging latency/tile,
// which the cycle model shows reproduces 135us and 167us respectively).
// Race-free: stage(t+1) overwrites buf[(t+1)&1] = tile t-1's data, whose
// compute all waves finished before the iter-(t-1) barrier; reads of tile t
// are covered by each wave's own vmcnt(0) before the shared barrier.
__global__ __launch_bounds__(256, 2) void gemm_fp8_kernel(
    const unsigned char* __restrict__ Aq,   // [8192][4096] e4m3 bytes
    const unsigned char* __restrict__ Bq,   // [4096][4096] e4m3 bytes
    const unsigned int* __restrict__ scb,   // absmax(x) bits
    const float* __restrict__ wscale,
    const float* __restrict__ bias,
    float* __restrict__ out) {
    __shared__ __align__(16) unsigned char lds[2 * 32768];  // buf: A @0 (16K), B @16384 (16K)
    const int tid = threadIdx.x;
    const int l = tid & 63, wv = tid >> 6, wm = wv >> 1, wn = wv & 1;
    const int bm = blockIdx.y, bn = blockIdx.x;

    // ---- scale (quant_fused finished before this kernel; plain load OK) ----
    const float am = __uint_as_float(*scb);
    const float scl = (fmaxf(am, 1e-12f) / FP8MAX) * wscale[0];

    // ---- staging addresses (gload_lds: linear LDS dest, pre-swizzled global
    //      source; wave w instr i covers rows 32w+8i..+8, lane l -> row l>>3,
    //      col 16(l&7) ^ ((l>>3)<<4) since row&7 == l>>3) ----
    const int srow = l >> 3;                      // 0..7
    const int scol = (16 * (l & 7)) ^ (srow << 4);
    const unsigned char* gA = Aq + (size_t)(bm * 128 + 32 * wv + srow) * 4096 + scol;
    const unsigned char* gB = Bq + (size_t)(bn * 128 + 32 * wv + srow) * 4096 + scol;
    const int ldsA = wv * 4096;                   // within-buffer dests
    const int ldsB = 16384 + wv * 4096;

    // ---- read-side offsets (round-3 proven, within-buffer) ----
    const int swzR = (l & 7) << 4;
    int aBase[2], bBase[2], rdOff[2][2][2];       // [i][s][half]
    #pragma unroll
    for (int i = 0; i < 2; ++i) {
        aBase[i] = (wm * 64 + i * 32 + (l & 31)) * 128;
        bBase[i] = 16384 + (wn * 64 + i * 32 + (l & 31)) * 128;
        #pragma unroll
        for (int s = 0; s < 2; ++s) {
            int off = s * 64 + (l >> 5) * 32;
            rdOff[i][s][0] = (off) ^ swzR;
            rdOff[i][s][1] = (off + 16) ^ swzR;
        }
    }

    floatx16 acc[2][2];
    #pragma unroll
    for (int i = 0; i < 2; ++i)
        #pragma unroll
        for (int j = 0; j < 2; ++j)
            acc[i][j] = (floatx16)0.f;

    auto stage = [&](int sel) {   // 8 gload_lds (4 A + 4 B), then advance K
        unsigned char* base = lds + sel * 32768;
        #pragma unroll
        for (int i = 0; i < 4; ++i) {
            __builtin_amdgcn_global_load_lds(
                (const __attribute__((address_space(1))) void*)(gA + i * 8 * 4096),
                (__attribute__((address_space(3))) void*)(base + ldsA + i * 1024), 16, 0, 0);
            __builtin_amdgcn_global_load_lds(
                (const __attribute__((address_space(1))) void*)(gB + i * 8 * 4096),
                (__attribute__((address_space(3))) void*)(base + ldsB + i * 1024), 16, 0, 0);
        }
        gA += 128;
        gB += 128;
    };

    auto compute = [&](int sel) {
        const unsigned char* base = lds + sel * 32768;
        int8v af[2][2], bf[2][2];  // [i|j][s]
        #pragma unroll
        for (int i = 0; i < 2; ++i) {
            #pragma unroll
            for (int s = 0; s < 2; ++s) {
                uint4 u0 = *(const uint4*)(base + aBase[i] + rdOff[i][s][0]);
                uint4 u1 = *(const uint4*)(base + aBase[i] + rdOff[i][s][1]);
                af[i][s] = pack8(u0, u1);
                uint4 v0 = *(const uint4*)(base + bBase[i] + rdOff[i][s][0]);
                uint4 v1 = *(const uint4*)(base + bBase[i] + rdOff[i][s][1]);
                bf[i][s] = pack8(v0, v1);
            }
        }
        #pragma unroll
        for (int s = 0; s < 2; ++s)
            #pragma unroll
            for (int i = 0; i < 2; ++i)
                #pragma unroll
                for (int j = 0; j < 2; ++j)
                    acc[i][j] = __builtin_amdgcn_mfma_scale_f32_32x32x64_f8f6f4(
                        af[i][s], bf[j][s], acc[i][j],
                        0 /*cbsz: fp8*/, 0 /*blgp: fp8*/,
                        0, 0x7F,   // scale A: E8M0 127 = 1.0
                        0, 0x7F);  // scale B: E8M0 127 = 1.0
    };

    // ---- prologue: tile 0 into buf0, drain once ----
    stage(0);
    asm volatile("s_waitcnt vmcnt(0)" ::: "memory");
    __builtin_amdgcn_s_barrier();

    // ---- main loop: issue -> compute -> wait -> barrier (one barrier/tile) ----
    for (int kt = 0; kt < 31; ++kt) {
        stage((kt + 1) & 1);                          // 8 loads fly under compute
        compute(kt & 1);
        asm volatile("s_waitcnt vmcnt(0)" ::: "memory");  // next tile landed
        __builtin_amdgcn_s_barrier();                 // visible to all waves
    }
    compute(1);                                       // tile 31

    // discriminator. Expected scl ~ 3.1e-6.
    float marker = 0.f;
    if (scl != scl || fabsf(scl) > 1e-1f) marker = 1000.f;
    else if (fabsf(scl) > 1e-4f) marker = 777.f;
    else if (fabsf(scl) < 1e-8f) marker = 333.f;

    float bj[2];
    #pragma unroll
    for (int j = 0; j < 2; ++j)
        bj[j] = bias[bn * 128 + wn * 64 + j * 32 + (l & 31)];

    // C/D map (32x32, shape-determined): col=lane&31, row=(reg&3)+8*(reg>>2)+4*(lane>>5)
    #pragma unroll
    for (int i = 0; i < 2; ++i) {
        #pragma unroll
        for (int rg = 0; rg < 4; ++rg) {
            #pragma unroll
            for (int rr = 0; rr < 4; ++rr) {
                int row = bm * 128 + wm * 64 + i * 32 + rg * 8 + rr + 4 * (l >> 5);
                float* orow = out + (size_t)row * N_DIM;
                #pragma unroll
                for (int j = 0; j < 2; ++j) {
                    int col = bn * 128 + wn * 64 + j * 32 + (l & 31);
                    float v = acc[i][j][rg * 4 + rr] * scl + bj[j];
                    if (marker != 0.f) v = marker;
                    else if (bj[j] != bj[j]) v = 111.f;
                    else if (v != v) v = 555.f;
                    orow[col] = v;
                }
            }
        }
    }
}

// ================= Fallback (in-place spread) path: round-6 verbatim =================

__global__ __launch_bounds__(256) void quant_w_kernel(unsigned char* wbuf) {
    const size_t t = (size_t)blockIdx.x * 256 + threadIdx.x;
    uint4* p = (uint4*)(wbuf + t * 256);
    uint4 r[16];
    #pragma unroll
    for (int i = 0; i < 16; ++i) r[i] = p[i];
    const float* f = (const float*)r;
    unsigned int o[32];
    #pragma unroll
    for (int i = 0; i < 16; ++i) {
        unsigned int b0 = f2bfbits(f[4 * i + 0]);
        unsigned int b1 = f2bfbits(f[4 * i + 1]);
        unsigned int b2 = f2bfbits(f[4 * i + 2]);
        unsigned int b3 = f2bfbits(f[4 * i + 3]);
        ((uint2*)o)[i] = make_uint2(b0 | (b1 << 16), b2 | (b3 << 16));
    }
    uint4* q = (uint4*)(wbuf + t * 256);
    #pragma unroll
    for (int i = 0; i < 8; ++i) q[i] = ((uint4*)o)[i];
}

__global__ __launch_bounds__(256) void quant_x_kernel(unsigned char* xbuf, unsigned char* wbuf) {
    const size_t t = (size_t)blockIdx.x * 256 + threadIdx.x;
    uint4* p = (uint4*)(xbuf + t * 256);
    uint4 r[16];
    #pragma unroll
    for (int i = 0; i < 16; ++i) r[i] = p[i];
    const float* f = (const float*)r;
    float vmax = 0.f;
    unsigned int o[32];
    #pragma unroll
    for (int i = 0; i < 16; ++i) {
        float a = f[4 * i + 0], b = f[4 * i + 1], c = f[4 * i + 2], d = f[4 * i + 3];
        vmax = fmaxf(vmax, fmaxf(fmaxf(fabsf(a), fabsf(b)), fmaxf(fabsf(c), fabsf(d))));
        ((uint2*)o)[i] = quant4(a, b, c, d);
    }
    uint4* q = (uint4*)(xbuf + t * 256);
    #pragma unroll
    for (int i = 0; i < 8; ++i) q[i] = ((uint4*)o)[i];
    #pragma unroll
    for (int off = 32; off >= 1; off >>= 1)
        vmax = fmaxf(vmax, __shfl_xor(vmax, off, 64));
    __shared__ float smax[4];
    if ((threadIdx.x & 63) == 0) smax[threadIdx.x >> 6] = vmax;
    __syncthreads();
    if (threadIdx.x == 0)
        *(float*)(wbuf + ((size_t)blockIdx.x + 1) * 256 + 128) =
            fmaxf(fmaxf(smax[0], smax[1]), fmaxf(smax[2], smax[3]));
}

__global__ __launch_bounds__(256) void scale_kernel(unsigned char* wbuf, const float* wscale) {
    float vmax = 0.f;
    for (int i = threadIdx.x; i < 2048; i += 256)
        vmax = fmaxf(vmax, *(const float*)(wbuf + ((size_t)i + 1) * 256 + 128));
    #pragma unroll
    for (int off = 32; off >= 1; off >>= 1)
        vmax = fmaxf(vmax, __shfl_xor(vmax, off, 64));
    __shared__ float smax[4];
    if ((threadIdx.x & 63) == 0) smax[threadIdx.x >> 6] = vmax;
    __syncthreads();
    if (threadIdx.x == 0) {
        float m = fmaxf(fmaxf(smax[0], smax[1]), fmaxf(smax[2], smax[3]));
        *(float*)(wbuf + 128) = (fmaxf(m, 1e-12f) / FP8MAX) * wscale[0];
        *(unsigned int*)(wbuf + 132) = CANARY;
    }
}

// ========== Fallback GEMM: round-6 structure, strides parametrized ==========
__global__ __launch_bounds__(256, 2) void gemm_bf16_kernel(
    const unsigned char* __restrict__ Aq,
    const unsigned char* __restrict__ Bq,
    int rs, int ktb,
    const unsigned char* __restrict__ scb,
    const float* __restrict__ bias,
    float* __restrict__ out) {
    __shared__ __align__(16) short lds[2 * 128 * 72];
    const int tid = threadIdx.x;
    const int l = tid & 63, wv = tid >> 6, wm = wv >> 1, wn = wv & 1;
    const int bm = blockIdx.y, bn = blockIdx.x;
    const int r = tid >> 1, kq = (tid & 1) * 64;

    const float scl = *(const float*)scb;
    const unsigned int canary = *(const unsigned int*)(scb + 4);

    const unsigned char* gA = Aq + (size_t)(bm * 128 + r) * rs + kq;
    const unsigned char* gB = Bq + (size_t)(bn * 128 + r) * rs + kq;
    short* sA = lds + r * 72 + kq / 2;
    short* sB = lds + 9216 + r * 72 + kq / 2;

    int aOff[4][2], bOff[4][2];
    #pragma unroll
    for (int i = 0; i < 4; ++i) {
        #pragma unroll
        for (int s = 0; s < 2; ++s) {
            int rowa = wm * 64 + i * 16 + (l & 15);
            aOff[i][s] = rowa * 72 + s * 32 + (l >> 4) * 8;
            int rowb = wn * 64 + i * 16 + (l & 15);
            bOff[i][s] = 9216 + rowb * 72 + s * 32 + (l >> 4) * 8;
        }
    }

    floatx4 acc[4][4];
    #pragma unroll
    for (int i = 0; i < 4; ++i)
        #pragma unroll
        for (int j = 0; j < 4; ++j)
            acc[i][j] = (floatx4)0.f;

    for (int kt = 0; kt < K_DIM / 64; ++kt) {
        uint4 a0 = *(const uint4*)(gA);
        uint4 a1 = *(const uint4*)(gA + 16);
        uint4 a2 = *(const uint4*)(gA + 32);
        uint4 a3 = *(const uint4*)(gA + 48);
        uint4 b0 = *(const uint4*)(gB);
        uint4 b1 = *(const uint4*)(gB + 16);
        uint4 b2 = *(const uint4*)(gB + 32);
        uint4 b3 = *(const uint4*)(gB + 48);
        gA += ktb;
        gB += ktb;
        __syncthreads();
        *(uint4*)(sA +  0) = a0;  *(uint4*)(sA +  8) = a1;
        *(uint4*)(sA + 16) = a2;  *(uint4*)(sA + 24) = a3;
        *(uint4*)(sB +  0) = b0;  *(uint4*)(sB +  8) = b1;
        *(uint4*)(sB + 16) = b2;  *(uint4*)(sB + 24) = b3;
        __syncthreads();

        short8 af[4][2], bf[4][2];
        #pragma unroll
        for (int i = 0; i < 4; ++i) {
            af[i][0] = *(const short8*)(lds + aOff[i][0]);
            af[i][1] = *(const short8*)(lds + aOff[i][1]);
            bf[i][0] = *(const short8*)(lds + bOff[i][0]);
            bf[i][1] = *(const short8*)(lds + bOff[i][1]);
        }
        #pragma unroll
        for (int s = 0; s < 2; ++s)
            #pragma unroll
            for (int i = 0; i < 4; ++i)
                #pragma unroll
                for (int j = 0; j < 4; ++j)
                    acc[i][j] = __builtin_amdgcn_mfma_f32_16x16x32_bf16(
                        af[i][s], bf[j][s], acc[i][j], 0, 0, 0);
    }

    float marker = 0.f;
    if (canary != CANARY) marker = 222.f;
    else if (scl != scl || fabsf(scl) > 1e-1f) marker = 1000.f;
    else if (fabsf(scl) > 1e-4f) marker = 777.f;
    else if (fabsf(scl) < 1e-8f) marker = 333.f;

    float bj[4];
    #pragma unroll
    for (int j = 0; j < 4; ++j) {
        int col = bn * 128 + wn * 64 + j * 16 + (l & 15);
        bj[j] = bias[col];
    }
    #pragma unroll
    for (int i = 0; i < 4; ++i) {
        #pragma unroll
        for (int rr = 0; rr < 4; ++rr) {
            int row = bm * 128 + wm * 64 + i * 16 + (l >> 4) * 4 + rr;
            float* orow = out + (size_t)row * N_DIM;
            #pragma unroll
            for (int j = 0; j < 4; ++j) {
                int col = bn * 128 + wn * 64 + j * 16 + (l & 15);
                float v = acc[i][j][rr] * scl + bj[j];
                if (marker != 0.f) v = marker;
                else if (bj[j] != bj[j]) v = 111.f;
                else if (v != v) v = 555.f;
                orow[col] = v;
            }
        }
    }
}

extern "C" void kernel_launch(void* const* d_in, const int* in_sizes, int n_in,
                              void* d_out, int out_size, void* d_ws, size_t ws_size,
                              hipStream_t stream) {
    unsigned char* x = (unsigned char*)d_in[0];   // fp32 [8192][4096] (fp16 promoted)
    unsigned char* w = (unsigned char*)d_in[1];   // fp32 exact-fp8 [4096][4096]
    const float* wscale = (const float*)d_in[2];  // fp32 [1]
    const float* bias = (const float*)d_in[3];    // fp32 [4096] (fp16 promoted)
    float* out = (float*)d_out;                   // fp32 [8192][4096]

    const size_t XQ8 = (size_t)M_DIM * K_DIM;     // 32MB fp8 x
    const size_t WQ8 = (size_t)N_DIM * K_DIM;     // 16MB fp8 w
    unsigned char* ws = (unsigned char*)d_ws;

    if (ws_size >= XQ8 + WQ8 + 64) {
        // ---- fp8 compact path: memset(scale) + fused prepass + MX-fp8 GEMM ----
        unsigned char* xq = ws;
        unsigned char* wq = ws + XQ8;
        unsigned int* scb = (unsigned int*)(ws + XQ8 + WQ8);
        hipMemsetAsync(scb, 0, 4, stream);        // seed for atomicMax (graph-safe)
        quant_fused<<<3072, 256, 0, stream>>>((const uint4*)x, (const uint4*)w,
                                              (uint4*)xq, (uint4*)wq, scb);
        gemm_fp8_kernel<<<dim3(N_DIM / 128, M_DIM / 128), 256, 0, stream>>>(
            xq, wq, scb, wscale, bias, out);
    } else {
        // ---- fallback: round-6 in-place spread path (proven) ----
        quant_w_kernel<<<1024, 256, 0, stream>>>(w);
        quant_x_kernel<<<2048, 256, 0, stream>>>(x, w);
        scale_kernel<<<1, 256, 0, stream>>>(w, wscale);
        gemm_bf16_kernel<<<dim3(N_DIM / 128, M_DIM / 128), 256, 0, stream>>>(
            x, w, 16384, 256, w + 128, bias, out);
    }
}

// Round 8
// 396.977 us; speedup vs baseline: 1.1403x; 1.0382x over previous
//
#include <hip/hip_runtime.h>
#include <hip/hip_bf16.h>
#include <stdint.h>

#define M_DIM 8192
#define N_DIM 4096
#define K_DIM 4096
#define FP8MAX 448.0f
#define CANARY 0x5CA1AB1Eu

typedef float floatx4 __attribute__((ext_vector_type(4)));
typedef float floatx16 __attribute__((ext_vector_type(16)));
typedef short short8 __attribute__((ext_vector_type(8)));
typedef int int8v __attribute__((ext_vector_type(8)));

// f32 -> bf16 bits, RNE. Exact for fp8-grid values. (fallback path)
__device__ __forceinline__ unsigned int f2bfbits(float f) {
    union { float f; unsigned int u; } v; v.f = f;
    return (v.u + 0x7fffu + ((v.u >> 16) & 1u)) >> 16;
}

// fp32x4 -> e4m3(RNE,sat) -> bf16x4 packed into uint2 (fallback path)
__device__ __forceinline__ uint2 quant4(float a, float b, float c, float d) {
    int p8 = __builtin_amdgcn_cvt_pk_fp8_f32(a, b, 0, false);
    p8 = __builtin_amdgcn_cvt_pk_fp8_f32(c, d, p8, true);
    float qa = __builtin_amdgcn_cvt_f32_fp8(p8, 0);
    float qb = __builtin_amdgcn_cvt_f32_fp8(p8, 1);
    float qc = __builtin_amdgcn_cvt_f32_fp8(p8, 2);
    float qd = __builtin_amdgcn_cvt_f32_fp8(p8, 3);
    return make_uint2(f2bfbits(qa) | (f2bfbits(qb) << 16),
                      f2bfbits(qc) | (f2bfbits(qd) << 16));
}

// uint4 of 4 fp32 -> 4 packed e4m3 bytes (RNE, saturating)
__device__ __forceinline__ unsigned int q4(uint4 v) {
    int p8 = __builtin_amdgcn_cvt_pk_fp8_f32(__uint_as_float(v.x), __uint_as_float(v.y), 0, false);
    p8 = __builtin_amdgcn_cvt_pk_fp8_f32(__uint_as_float(v.z), __uint_as_float(v.w), p8, true);
    return (unsigned int)p8;
}

__device__ __forceinline__ float amax4(uint4 v, float m) {
    float a = fabsf(__uint_as_float(v.x)), b = fabsf(__uint_as_float(v.y));
    float c = fabsf(__uint_as_float(v.z)), d = fabsf(__uint_as_float(v.w));
    return fmaxf(m, fmaxf(fmaxf(a, b), fmaxf(c, d)));
}

// ============ Fused prepass: w-quant (blocks 0..1023) + x-quant+absmax ============
// Fully coalesced: each thread handles ONE uint4 (16B in, 4B out) per iter —
// wave loads 1KB contiguous per instr, stores 256B contiguous.
// x absmax via device-scope atomicMax on positive-float bits (monotonic for
// >=0 floats); scb[0] pre-zeroed by a 4-byte hipMemsetAsync in kernel_launch.
__global__ __launch_bounds__(256) void quant_fused(const uint4* __restrict__ x,
                                                   const uint4* __restrict__ w,
                                                   unsigned int* __restrict__ xq,
                                                   unsigned int* __restrict__ wq,
                                                   unsigned int* __restrict__ scb) {
    if (blockIdx.x < 1024) {
        const int tid = blockIdx.x * 256 + threadIdx.x;        // 262144 threads
        #pragma unroll 4
        for (int c = tid; c < (N_DIM * K_DIM) / 4; c += 1024 * 256)
            wq[c] = q4(w[c]);
    } else {
        const int b = blockIdx.x - 1024;                        // 0..2047
        const int tid = b * 256 + threadIdx.x;                  // 524288 threads
        float vmax = 0.f;
        #pragma unroll 4
        for (int c = tid; c < (M_DIM * K_DIM) / 4; c += 2048 * 256) {
            uint4 v = x[c];
            vmax = amax4(v, vmax);
            xq[c] = q4(v);
        }
        #pragma unroll
        for (int off = 32; off >= 1; off >>= 1)
            vmax = fmaxf(vmax, __shfl_xor(vmax, off, 64));
        __shared__ float smax[4];
        if ((threadIdx.x & 63) == 0) smax[threadIdx.x >> 6] = vmax;
        __syncthreads();
        if (threadIdx.x == 0) {
            float m = fmaxf(fmaxf(smax[0], smax[1]), fmaxf(smax[2], smax[3]));
            atomicMax(scb, __float_as_uint(m));   // bits monotonic for m >= 0
        }
    }
}

__device__ __forceinline__ int8v pack8(uint4 u0, uint4 u1) {
    int8v r;
    r[0] = (int)u0.x; r[1] = (int)u0.y; r[2] = (int)u0.z; r[3] = (int)u0.w;
    r[4] = (int)u1.x; r[5] = (int)u1.y; r[6] = (int)u1.z; r[7] = (int)u1.w;
    return r;
}

// ========== FP8 GEMM: round-3 proven kernel (135.6us, MfmaUtil 50%) verbatim,
// plus: (a) 2x4 XCD-aware bijective block swizzle (r3 had none; raw RR makes
// each A-panel hit ~8 XCD L2s — the (2,4) partition cuts model-FETCH
// 160->128MB), (b) __launch_bounds__(256,4): r3 sat at exactly 64V+64A =
// 128 regs/wave = the 4-waves/SIMD cap but only ~3 blocks co-resided; declare
// the intent so the 4th block (grid = exactly 8/CU of work) can land.
// Main loop, swizzle, staging map, fragment reads: byte-identical to r3.
__global__ __launch_bounds__(256, 4) void gemm_fp8_kernel(
    const unsigned char* __restrict__ Aq,   // [8192][4096] e4m3 bytes
    const unsigned char* __restrict__ Bq,   // [4096][4096] e4m3 bytes
    const unsigned int* __restrict__ scb,   // absmax(x) bits
    const float* __restrict__ wscale,
    const float* __restrict__ bias,
    float* __restrict__ out) {
    __shared__ __align__(16) unsigned char lds[2 * 128 * 128];  // A @0, B @16384
    const int tid = threadIdx.x;
    const int l = tid & 63, wv = tid >> 6, wm = wv >> 1, wn = wv & 1;

    // ---- 2x4 XCD partition of the 64(bm) x 32(bn) grid; 2048 % 8 == 0 ----
    const int lin = blockIdx.y * 32 + blockIdx.x;   // 0..2047
    const int xcd = lin & 7, loc = lin >> 3;        // xcd row r=xcd>>2, col c=xcd&3
    const int bm = (xcd >> 2) * 32 + (loc >> 3);    // 32-bm stripe per xcd-row
    const int bn = (xcd & 3) * 8 + (loc & 7);       // 8-bn stripe per xcd-col

    // ---- scale (quant_fused finished before this kernel; plain load OK) ----
    const float am = __uint_as_float(*scb);
    const float scl = (fmaxf(am, 1e-12f) / FP8MAX) * wscale[0];

    // ---- staging addresses (gload_lds: linear LDS dest, pre-swizzled global
    //      source; wave w instr i covers rows 32w+8i..+8, lane l -> row l>>3,
    //      col 16(l&7) ^ ((l>>3)<<4) since row&7 == l>>3) ----
    const int srow = l >> 3;                      // 0..7
    const int scol = (16 * (l & 7)) ^ (srow << 4);
    const unsigned char* gA = Aq + (size_t)(bm * 128 + 32 * wv + srow) * 4096 + scol;
    const unsigned char* gB = Bq + (size_t)(bn * 128 + 32 * wv + srow) * 4096 + scol;
    unsigned char* sAw = lds + wv * 4096;         // wave-uniform LDS bases
    unsigned char* sBw = lds + 16384 + wv * 4096;

    // ---- read-side offsets (r3 proven) ----
    const int swzR = (l & 7) << 4;
    int aBase[2], bBase[2], rdOff[2][2][2];       // [i][s][half]
    #pragma unroll
    for (int i = 0; i < 2; ++i) {
        aBase[i] = (wm * 64 + i * 32 + (l & 31)) * 128;
        bBase[i] = 16384 + (wn * 64 + i * 32 + (l & 31)) * 128;
        #pragma unroll
        for (int s = 0; s < 2; ++s) {
            int off = s * 64 + (l >> 5) * 32;
            rdOff[i][s][0] = (off) ^ swzR;
            rdOff[i][s][1] = (off + 16) ^ swzR;
        }
    }

    floatx16 acc[2][2];
    #pragma unroll
    for (int i = 0; i < 2; ++i)
        #pragma unroll
        for (int j = 0; j < 2; ++j)
            acc[i][j] = (floatx16)0.f;

    for (int kt = 0; kt < K_DIM / 128; ++kt) {
        __syncthreads();           // all waves done reading previous tile
        #pragma unroll
        for (int i = 0; i < 4; ++i) {
            __builtin_amdgcn_global_load_lds(
                (const __attribute__((address_space(1))) void*)(gA + i * 8 * 4096),
                (__attribute__((address_space(3))) void*)(sAw + i * 1024), 16, 0, 0);
            __builtin_amdgcn_global_load_lds(
                (const __attribute__((address_space(1))) void*)(gB + i * 8 * 4096),
                (__attribute__((address_space(3))) void*)(sBw + i * 1024), 16, 0, 0);
        }
        gA += 128;
        gB += 128;
        __syncthreads();           // vmcnt(0) drain + barrier: tiles visible

        int8v af[2][2], bf[2][2];  // [i|j][s]
        #pragma unroll
        for (int i = 0; i < 2; ++i) {
            #pragma unroll
            for (int s = 0; s < 2; ++s) {
                uint4 u0 = *(const uint4*)(lds + aBase[i] + rdOff[i][s][0]);
                uint4 u1 = *(const uint4*)(lds + aBase[i] + rdOff[i][s][1]);
                af[i][s] = pack8(u0, u1);
                uint4 v0 = *(const uint4*)(lds + bBase[i] + rdOff[i][s][0]);
                uint4 v1 = *(const uint4*)(lds + bBase[i] + rdOff[i][s][1]);
                bf[i][s] = pack8(v0, v1);
            }
        }
        #pragma unroll
        for (int s = 0; s < 2; ++s)
            #pragma unroll
            for (int i = 0; i < 2; ++i)
                #pragma unroll
                for (int j = 0; j < 2; ++j)
                    acc[i][j] = __builtin_amdgcn_mfma_scale_f32_32x32x64_f8f6f4(
                        af[i][s], bf[j][s], acc[i][j],
                        0 /*cbsz: fp8*/, 0 /*blgp: fp8*/,
                        0, 0x7F,   // scale A: E8M0 127 = 1.0
                        0, 0x7F);  // scale B: E8M0 127 = 1.0
    }

    // discriminator. Expected scl ~ 3.1e-6.
    float marker = 0.f;
    if (scl != scl || fabsf(scl) > 1e-1f) marker = 1000.f;
    else if (fabsf(scl) > 1e-4f) marker = 777.f;
    else if (fabsf(scl) < 1e-8f) marker = 333.f;

    float bj[2];
    #pragma unroll
    for (int j = 0; j < 2; ++j)
        bj[j] = bias[bn * 128 + wn * 64 + j * 32 + (l & 31)];

    // C/D map (32x32, shape-determined): col=lane&31, row=(reg&3)+8*(reg>>2)+4*(lane>>5)
    #pragma unroll
    for (int i = 0; i < 2; ++i) {
        #pragma unroll
        for (int rg = 0; rg < 4; ++rg) {
            #pragma unroll
            for (int rr = 0; rr < 4; ++rr) {
                int row = bm * 128 + wm * 64 + i * 32 + rg * 8 + rr + 4 * (l >> 5);
                float* orow = out + (size_t)row * N_DIM;
                #pragma unroll
                for (int j = 0; j < 2; ++j) {
                    int col = bn * 128 + wn * 64 + j * 32 + (l & 31);
                    float v = acc[i][j][rg * 4 + rr] * scl + bj[j];
                    if (marker != 0.f) v = marker;
                    else if (bj[j] != bj[j]) v = 111.f;
                    else if (v != v) v = 555.f;
                    orow[col] = v;
                }
            }
        }
    }
}

// ================= Fallback (in-place spread) path: round-6 verbatim =================

__global__ __launch_bounds__(256) void quant_w_kernel(unsigned char* wbuf) {
    const size_t t = (size_t)blockIdx.x * 256 + threadIdx.x;
    uint4* p = (uint4*)(wbuf + t * 256);
    uint4 r[16];
    #pragma unroll
    for (int i = 0; i < 16; ++i) r[i] = p[i];
    const float* f = (const float*)r;
    unsigned int o[32];
    #pragma unroll
    for (int i = 0; i < 16; ++i) {
        unsigned int b0 = f2bfbits(f[4 * i + 0]);
        unsigned int b1 = f2bfbits(f[4 * i + 1]);
        unsigned int b2 = f2bfbits(f[4 * i + 2]);
        unsigned int b3 = f2bfbits(f[4 * i + 3]);
        ((uint2*)o)[i] = make_uint2(b0 | (b1 << 16), b2 | (b3 << 16));
    }
    uint4* q = (uint4*)(wbuf + t * 256);
    #pragma unroll
    for (int i = 0; i < 8; ++i) q[i] = ((uint4*)o)[i];
}

__global__ __launch_bounds__(256) void quant_x_kernel(unsigned char* xbuf, unsigned char* wbuf) {
    const size_t t = (size_t)blockIdx.x * 256 + threadIdx.x;
    uint4* p = (uint4*)(xbuf + t * 256);
    uint4 r[16];
    #pragma unroll
    for (int i = 0; i < 16; ++i) r[i] = p[i];
    const float* f = (const float*)r;
    float vmax = 0.f;
    unsigned int o[32];
    #pragma unroll
    for (int i = 0; i < 16; ++i) {
        float a = f[4 * i + 0], b = f[4 * i + 1], c = f[4 * i + 2], d = f[4 * i + 3];
        vmax = fmaxf(vmax, fmaxf(fmaxf(fabsf(a), fabsf(b)), fmaxf(fabsf(c), fabsf(d))));
        ((uint2*)o)[i] = quant4(a, b, c, d);
    }
    uint4* q = (uint4*)(xbuf + t * 256);
    #pragma unroll
    for (int i = 0; i < 8; ++i) q[i] = ((uint4*)o)[i];
    #pragma unroll
    for (int off = 32; off >= 1; off >>= 1)
        vmax = fmaxf(vmax, __shfl_xor(vmax, off, 64));
    __shared__ float smax[4];
    if ((threadIdx.x & 63) == 0) smax[threadIdx.x >> 6] = vmax;
    __syncthreads();
    if (threadIdx.x == 0)
        *(float*)(wbuf + ((size_t)blockIdx.x + 1) * 256 + 128) =
            fmaxf(fmaxf(smax[0], smax[1]), fmaxf(smax[2], smax[3]));
}

__global__ __launch_bounds__(256) void scale_kernel(unsigned char* wbuf, const float* wscale) {
    float vmax = 0.f;
    for (int i = threadIdx.x; i < 2048; i += 256)
        vmax = fmaxf(vmax, *(const float*)(wbuf + ((size_t)i + 1) * 256 + 128));
    #pragma unroll
    for (int off = 32; off >= 1; off >>= 1)
        vmax = fmaxf(vmax, __shfl_xor(vmax, off, 64));
    __shared__ float smax[4];
    if ((threadIdx.x & 63) == 0) smax[threadIdx.x >> 6] = vmax;
    __syncthreads();
    if (threadIdx.x == 0) {
        float m = fmaxf(fmaxf(smax[0], smax[1]), fmaxf(smax[2], smax[3]));
        *(float*)(wbuf + 128) = (fmaxf(m, 1e-12f) / FP8MAX) * wscale[0];
        *(unsigned int*)(wbuf + 132) = CANARY;
    }
}

// ========== Fallback GEMM: round-6 structure, strides parametrized ==========
__global__ __launch_bounds__(256, 2) void gemm_bf16_kernel(
    const unsigned char* __restrict__ Aq,
    const unsigned char* __restrict__ Bq,
    int rs, int ktb,
    const unsigned char* __restrict__ scb,
    const float* __restrict__ bias,
    float* __restrict__ out) {
    __shared__ __align__(16) short lds[2 * 128 * 72];
    const int tid = threadIdx.x;
    const int l = tid & 63, wv = tid >> 6, wm = wv >> 1, wn = wv & 1;
    const int bm = blockIdx.y, bn = blockIdx.x;
    const int r = tid >> 1, kq = (tid & 1) * 64;

    const float scl = *(const float*)scb;
    const unsigned int canary = *(const unsigned int*)(scb + 4);

    const unsigned char* gA = Aq + (size_t)(bm * 128 + r) * rs + kq;
    const unsigned char* gB = Bq + (size_t)(bn * 128 + r) * rs + kq;
    short* sA = lds + r * 72 + kq / 2;
    short* sB = lds + 9216 + r * 72 + kq / 2;

    int aOff[4][2], bOff[4][2];
    #pragma unroll
    for (int i = 0; i < 4; ++i) {
        #pragma unroll
        for (int s = 0; s < 2; ++s) {
            int rowa = wm * 64 + i * 16 + (l & 15);
            aOff[i][s] = rowa * 72 + s * 32 + (l >> 4) * 8;
            int rowb = wn * 64 + i * 16 + (l & 15);
            bOff[i][s] = 9216 + rowb * 72 + s * 32 + (l >> 4) * 8;
        }
    }

    floatx4 acc[4][4];
    #pragma unroll
    for (int i = 0; i < 4; ++i)
        #pragma unroll
        for (int j = 0; j < 4; ++j)
            acc[i][j] = (floatx4)0.f;

    for (int kt = 0; kt < K_DIM / 64; ++kt) {
        uint4 a0 = *(const uint4*)(gA);
        uint4 a1 = *(const uint4*)(gA + 16);
        uint4 a2 = *(const uint4*)(gA + 32);
        uint4 a3 = *(const uint4*)(gA + 48);
        uint4 b0 = *(const uint4*)(gB);
        uint4 b1 = *(const uint4*)(gB + 16);
        uint4 b2 = *(const uint4*)(gB + 32);
        uint4 b3 = *(const uint4*)(gB + 48);
        gA += ktb;
        gB += ktb;
        __syncthreads();
        *(uint4*)(sA +  0) = a0;  *(uint4*)(sA +  8) = a1;
        *(uint4*)(sA + 16) = a2;  *(uint4*)(sA + 24) = a3;
        *(uint4*)(sB +  0) = b0;  *(uint4*)(sB +  8) = b1;
        *(uint4*)(sB + 16) = b2;  *(uint4*)(sB + 24) = b3;
        __syncthreads();

        short8 af[4][2], bf[4][2];
        #pragma unroll
        for (int i = 0; i < 4; ++i) {
            af[i][0] = *(const short8*)(lds + aOff[i][0]);
            af[i][1] = *(const short8*)(lds + aOff[i][1]);
            bf[i][0] = *(const short8*)(lds + bOff[i][0]);
            bf[i][1] = *(const short8*)(lds + bOff[i][1]);
        }
        #pragma unroll
        for (int s = 0; s < 2; ++s)
            #pragma unroll
            for (int i = 0; i < 4; ++i)
                #pragma unroll
                for (int j = 0; j < 4; ++j)
                    acc[i][j] = __builtin_amdgcn_mfma_f32_16x16x32_bf16(
                        af[i][s], bf[j][s], acc[i][j], 0, 0, 0);
    }

    float marker = 0.f;
    if (canary != CANARY) marker = 222.f;
    else if (scl != scl || fabsf(scl) > 1e-1f) marker = 1000.f;
    else if (fabsf(scl) > 1e-4f) marker = 777.f;
    else if (fabsf(scl) < 1e-8f) marker = 333.f;

    float bj[4];
    #pragma unroll
    for (int j = 0; j < 4; ++j) {
        int col = bn * 128 + wn * 64 + j * 16 + (l & 15);
        bj[j] = bias[col];
    }
    #pragma unroll
    for (int i = 0; i < 4; ++i) {
        #pragma unroll
        for (int rr = 0; rr < 4; ++rr) {
            int row = bm * 128 + wm * 64 + i * 16 + (l >> 4) * 4 + rr;
            float* orow = out + (size_t)row * N_DIM;
            #pragma unroll
            for (int j = 0; j < 4; ++j) {
                int col = bn * 128 + wn * 64 + j * 16 + (l & 15);
                float v = acc[i][j][rr] * scl + bj[j];
                if (marker != 0.f) v = marker;
                else if (bj[j] != bj[j]) v = 111.f;
                else if (v != v) v = 555.f;
                orow[col] = v;
            }
        }
    }
}

extern "C" void kernel_launch(void* const* d_in, const int* in_sizes, int n_in,
                              void* d_out, int out_size, void* d_ws, size_t ws_size,
                              hipStream_t stream) {
    unsigned char* x = (unsigned char*)d_in[0];   // fp32 [8192][4096] (fp16 promoted)
    unsigned char* w = (unsigned char*)d_in[1];   // fp32 exact-fp8 [4096][4096]
    const float* wscale = (const float*)d_in[2];  // fp32 [1]
    const float* bias = (const float*)d_in[3];    // fp32 [4096] (fp16 promoted)
    float* out = (float*)d_out;                   // fp32 [8192][4096]

    const size_t XQ8 = (size_t)M_DIM * K_DIM;     // 32MB fp8 x
    const size_t WQ8 = (size_t)N_DIM * K_DIM;     // 16MB fp8 w
    unsigned char* ws = (unsigned char*)d_ws;

    if (ws_size >= XQ8 + WQ8 + 64) {
        // ---- fp8 compact path: memset(scale) + fused prepass + MX-fp8 GEMM ----
        unsigned char* xq = ws;
        unsigned char* wq = ws + XQ8;
        unsigned int* scb = (unsigned int*)(ws + XQ8 + WQ8);
        hipMemsetAsync(scb, 0, 4, stream);        // seed for atomicMax (graph-safe)
        quant_fused<<<3072, 256, 0, stream>>>((const uint4*)x, (const uint4*)w,
                                              (unsigned int*)xq, (unsigned int*)wq, scb);
        gemm_fp8_kernel<<<dim3(N_DIM / 128, M_DIM / 128), 256, 0, stream>>>(
            xq, wq, scb, wscale, bias, out);
    } else {
        // ---- fallback: round-6 in-place spread path (proven) ----
        quant_w_kernel<<<1024, 256, 0, stream>>>(w);
        quant_x_kernel<<<2048, 256, 0, stream>>>(x, w);
        scale_kernel<<<1, 256, 0, stream>>>(w, wscale);
        gemm_bf16_kernel<<<dim3(N_DIM / 128, M_DIM / 128), 256, 0, stream>>>(
            x, w, 16384, 256, w + 128, bias, out);
    }
}